// Round 9
// baseline (140.665 us; speedup 1.0000x reference)
//
#include <hip/hip_runtime.h>
#include <hip/hip_bf16.h>
#include <math.h>

typedef __attribute__((ext_vector_type(8))) __bf16 bf16x8;
typedef __attribute__((ext_vector_type(4))) short short4v;
typedef __attribute__((ext_vector_type(4))) float f32x4;
typedef __attribute__((ext_vector_type(16))) float f32x16;
typedef __attribute__((ext_vector_type(4))) unsigned short ushort4v;
typedef __attribute__((ext_vector_type(8))) unsigned short ushort8;
typedef __attribute__((ext_vector_type(4))) unsigned int uint4v;

#define LOG2E 1.44269504088896340736f

static __device__ __forceinline__ unsigned short f2bf(float f) {
  unsigned int u = __float_as_uint(f);
  return (unsigned short)((u + 0x7fffu + ((u >> 16) & 1u)) >> 16);
}
static __device__ __forceinline__ short bfbits(float f) {
  __bf16 h = (__bf16)f;
  return __builtin_bit_cast(short, h);
}
static __device__ __forceinline__ float bf2f(unsigned short u) {
  unsigned int v = ((unsigned int)u) << 16;
  return __builtin_bit_cast(float, v);
}

static __device__ __forceinline__ void gload16(const unsigned short* g, void* l) {
  __builtin_amdgcn_global_load_lds(
      (const __attribute__((address_space(1))) unsigned int*)g,
      (__attribute__((address_space(3))) unsigned int*)l, 16, 0, 0);
}

// ---------------- fused prep: all casts + RoPE table ----------------
__global__ __launch_bounds__(256) void prep_kernel(
    const float* __restrict__ x, const float* __restrict__ Wq,
    const float* __restrict__ Wk, const float* __restrict__ Wv,
    const float* __restrict__ Wo,
    unsigned short* __restrict__ xb, unsigned short* __restrict__ wqkv,
    unsigned short* __restrict__ wo_b, float* __restrict__ tab) {
  const int bx = blockIdx.x, tid = threadIdx.x;
  if (bx < 6656) {
    const float* src;
    unsigned short* dst;
    int i;
    if (bx < 4096)       { src = x;  dst = xb;             i = bx * 256 + tid; }
    else if (bx < 5120)  { src = Wq; dst = wqkv;           i = (bx - 4096) * 256 + tid; }
    else if (bx < 5376)  { src = Wk; dst = wqkv + 1048576; i = (bx - 5120) * 256 + tid; }
    else if (bx < 5632)  { src = Wv; dst = wqkv + 1310720; i = (bx - 5376) * 256 + tid; }
    else                 { src = Wo; dst = wo_b;           i = (bx - 5632) * 256 + tid; }
    float4 v = reinterpret_cast<const float4*>(src)[i];
    ushort4v o;
    o.x = f2bf(v.x); o.y = f2bf(v.y); o.z = f2bf(v.z); o.w = f2bf(v.w);
    reinterpret_cast<ushort4v*>(dst)[i] = o;
  } else {
    int i = (bx - 6656) * 256 + tid;  // 65536 = 2048*32
    int s = i >> 5, d = i & 31;
    float invf = powf(10000.f, -(float)d / 32.f);
    float fr = (float)s * invf;
    tab[s * 64 + d] = cosf(fr);
    tab[s * 64 + 32 + d] = sinf(fr);
  }
}

// ---------------- bf16 GEMM: C[M,N] = A[M,K] * B[N,K]^T ----------------
// BM=64, BN=128, BK=64; 4 waves (2x2), wave tile 32x64 = acc[2][4].
template <bool B16OUT>
__global__ __launch_bounds__(256) void gemm_bt_kernel(
    const unsigned short* __restrict__ A, const unsigned short* __restrict__ B,
    void* __restrict__ Cv, int M, int N, int K, int nbn) {
  __shared__ unsigned short sA[64 * 64];
  __shared__ unsigned short sB[128 * 64];
  const int t = threadIdx.x;
  const int lane = t & 63;
  const int w = t >> 6;
  const int bm = blockIdx.x / nbn, bn = blockIdx.x % nbn;
  const long m0 = (long)bm * 64, n0 = (long)bn * 128;
  const int wm = (w >> 1) * 32, wn = (w & 1) * 64;
  const int lr = lane & 15, lg = lane >> 4;
  f32x4 acc[2][4];
#pragma unroll
  for (int i = 0; i < 2; i++)
#pragma unroll
    for (int j = 0; j < 4; j++) acc[i][j] = (f32x4){0.f, 0.f, 0.f, 0.f};

  for (int k0 = 0; k0 < K; k0 += 64) {
#pragma unroll
    for (int i = 0; i < 2; i++) {
      int chunk = i * 256 + t;
      int r = chunk >> 3;
      int c = (chunk & 7) << 3;
      gload16(A + (m0 + r) * (long)K + k0 + c, (char*)sA + chunk * 16);
    }
#pragma unroll
    for (int i = 0; i < 4; i++) {
      int chunk = i * 256 + t;
      int r = chunk >> 3;
      int c = (chunk & 7) << 3;
      gload16(B + (n0 + r) * (long)K + k0 + c, (char*)sB + chunk * 16);
    }
    __syncthreads();
#pragma unroll
    for (int kk = 0; kk < 2; ++kk) {
      bf16x8 af[2], bfr[4];
#pragma unroll
      for (int m = 0; m < 2; m++)
        af[m] = *(const bf16x8*)&sA[(wm + m * 16 + lr) * 64 + kk * 32 + lg * 8];
#pragma unroll
      for (int n = 0; n < 4; n++)
        bfr[n] = *(const bf16x8*)&sB[(wn + n * 16 + lr) * 64 + kk * 32 + lg * 8];
#pragma unroll
      for (int m = 0; m < 2; m++)
#pragma unroll
        for (int n = 0; n < 4; n++)
          acc[m][n] = __builtin_amdgcn_mfma_f32_16x16x32_bf16(af[m], bfr[n], acc[m][n], 0, 0, 0);
    }
    __syncthreads();
  }
#pragma unroll
  for (int m = 0; m < 2; m++) {
#pragma unroll
    for (int n = 0; n < 4; n++) {
      long col = n0 + wn + n * 16 + lr;
#pragma unroll
      for (int j = 0; j < 4; j++) {
        long row = m0 + wm + m * 16 + lg * 4 + j;
        if (B16OUT)
          ((unsigned short*)Cv)[row * N + col] = f2bf(acc[m][n][j]);
        else
          ((float*)Cv)[row * N + col] = acc[m][n][j];
      }
    }
  }
}

// ---------------- RMSNorm + RoPE + gain + pack (Q/K only, bf16 in) ----------------
__global__ __launch_bounds__(256) void pack_kernel(
    const unsigned short* __restrict__ qkv, const float* __restrict__ tab,
    const float* __restrict__ qg,
    unsigned short* __restrict__ qb, unsigned short* __restrict__ kb) {
  const int wid = (blockIdx.x * 256 + threadIdx.x) >> 6;
  const int lane = threadIdx.x & 63;
  const int row = wid / 20;      // b*2048 + s
  const int u = wid % 20;        // 0..15 q heads, 16..19 k heads
  const int b = row >> 11, s = row & 2047;
  float v;
  if (u < 16) v = bf2f(qkv[(size_t)row * 1536 + u * 64 + lane]);
  else        v = bf2f(qkv[(size_t)row * 1536 + 1024 + (u - 16) * 64 + lane]);
  float ss = v * v;
#pragma unroll
  for (int m = 32; m >= 1; m >>= 1) ss += __shfl_xor(ss, m);
  float n = v * rsqrtf(ss * (1.0f / 64.0f) + 1.1920929e-07f);
  int i = lane & 31;
  float c = tab[s * 64 + i], sn = tab[s * 64 + 32 + i];
  float p = __shfl_xor(n, 32);
  float o = (lane < 32) ? (n * c + p * sn) : (n * c - p * sn);
  if (u < 16) {
    o *= qg[u] * (0.125f * LOG2E);
    qb[((size_t)(b * 16 + u) * 2048 + s) * 64 + lane] = f2bf(o);
  } else {
    kb[((size_t)(b * 4 + (u - 16)) * 2048 + s) * 64 + lane] = f2bf(o);
  }
}

// ---------------- V transpose: qkv v-slice [s][d] -> vtb [d][s] ----------------
__global__ __launch_bounds__(256) void vpack_kernel(
    const unsigned short* __restrict__ qkv, unsigned short* __restrict__ vtb) {
  __shared__ unsigned short sT[64 * 65];
  const int tid = threadIdx.x;
  const int bhk = blockIdx.x >> 5;          // 0..7 = b*4+hk
  const int st = blockIdx.x & 31;           // s-tile
  const int b = bhk >> 2, hk = bhk & 3;
  const int r = tid >> 2, cg = (tid & 3) << 4;
  const unsigned short* src = qkv + (size_t)(b * 2048 + st * 64 + r) * 1536 + 1280 + hk * 64 + cg;
  ushort8 v0 = *(const ushort8*)src;
  ushort8 v1 = *(const ushort8*)(src + 8);
#pragma unroll
  for (int k = 0; k < 8; ++k) sT[r * 65 + cg + k] = v0[k];
#pragma unroll
  for (int k = 0; k < 8; ++k) sT[r * 65 + cg + 8 + k] = v1[k];
  __syncthreads();
  const int d = tid >> 2, sg = (tid & 3) << 4;
  ushort8 o0, o1;
#pragma unroll
  for (int k = 0; k < 8; ++k) o0[k] = sT[(sg + k) * 65 + d];
#pragma unroll
  for (int k = 0; k < 8; ++k) o1[k] = sT[(sg + 8 + k) * 65 + d];
  unsigned short* dst = vtb + ((size_t)(bhk * 64 + d)) * 2048 + st * 64 + sg;
  *(ushort8*)dst = o0;
  *(ushort8*)(dst + 8) = o1;
}

// ---------------- causal flash attention: 32x32x16 MFMA structure ----------------
// 2 waves / 128 threads; wave = 32 q rows; block = 64 q rows of one (b,h).
// KVBLK=64 double-buffered LDS (32KB). Q in registers; K,V^T frags from LDS.
// S^T via mfma(K,Q) (D: col=q=lane&31, row=kv=(reg&3)+8*(reg>>2)+4*(lane>>5));
// P^T redistributed in-register via cvt_pk_bf16 + permlane32_swap (T12);
// PV via mfma(V^T, P^T). Fixed-max softmax (M=11.7*|g|), heavy-first dispatch.
__global__ __launch_bounds__(128) void attn_kernel(
    const unsigned short* __restrict__ qb, const unsigned short* __restrict__ kb,
    const unsigned short* __restrict__ vtb, unsigned short* __restrict__ yb,
    const float* __restrict__ qg) {
  __shared__ unsigned short sK[2][64 * 64];
  __shared__ unsigned short sV[2][64 * 64];
  const int tid = threadIdx.x;
  const int lane = tid & 63;
  const int w = tid >> 6;                  // 0..1
  const int qt = 31 - (blockIdx.x >> 5);   // heavy-first
  const int bh = blockIdx.x & 31;
  const int h = bh & 15;
  const int b = bh >> 4;
  const float M = 11.7f * fabsf(qg[h]);
  const int q0 = qt * 64 + w * 32;
  const unsigned short* Q  = qb  + (size_t)(b * 16 + h) * 2048 * 64;
  const unsigned short* Kp = kb  + (size_t)(b * 4 + (h >> 2)) * 2048 * 64;
  const unsigned short* Vp = vtb + (size_t)(b * 4 + (h >> 2)) * 64 * 2048;
  const int ql = lane & 31;                // q column (and A-operand row)
  const int hh = lane >> 5;                // k-slot half
  // Q B-operand frags: lane holds Q[q0+ql][dsl*16 + hh*8 .. +7], dsl=0..3
  bf16x8 qf[4];
#pragma unroll
  for (int dsl = 0; dsl < 4; ++dsl)
    qf[dsl] = *(const bf16x8*)(Q + (size_t)(q0 + ql) * 64 + dsl * 16 + hh * 8);
  f32x16 acc[2];
#pragma unroll
  for (int e = 0; e < 16; ++e) { acc[0][e] = 0.f; acc[1][e] = 0.f; }
  float lsum = 0.f;
  const int nt = qt + 1;

  // staging: 128 threads × (4 K + 4 V) 16B chunks; rows r0+16i share (r&7) swizzle
  const int r0 = tid >> 3, c0 = tid & 7;
  const int swz = ((c0 ^ (r0 & 7)) << 3);
  const unsigned short* gK = Kp + (size_t)r0 * 64 + swz;
  const unsigned short* gV = Vp + (size_t)r0 * 2048 + swz;

#define STAGE_TILE(bufi)                                              \
  do {                                                                \
    gload16(gK,             (char*)&sK[bufi][0] + tid * 16);          \
    gload16(gK + 16 * 64,   (char*)&sK[bufi][0] + (tid + 128) * 16);  \
    gload16(gK + 32 * 64,   (char*)&sK[bufi][0] + (tid + 256) * 16);  \
    gload16(gK + 48 * 64,   (char*)&sK[bufi][0] + (tid + 384) * 16);  \
    gload16(gV,             (char*)&sV[bufi][0] + tid * 16);          \
    gload16(gV + 16 * 2048, (char*)&sV[bufi][0] + (tid + 128) * 16);  \
    gload16(gV + 32 * 2048, (char*)&sV[bufi][0] + (tid + 256) * 16);  \
    gload16(gV + 48 * 2048, (char*)&sV[bufi][0] + (tid + 384) * 16);  \
  } while (0)

  STAGE_TILE(0);
  gK += 64 * 64; gV += 64;

  int cur = 0;
  for (int t = 0; t < nt; ++t) {
    __syncthreads();   // drains vmcnt: buf[cur] staged; buf[cur^1] free
    if (t + 1 < nt) {  // prefetch next tile; in flight across this compute phase
      STAGE_TILE(cur ^ 1);
      gK += 64 * 64; gV += 64;
    }
    const unsigned short* sKc = &sK[cur][0];
    const unsigned short* sVc = &sV[cur][0];
    // ---- QK^T: 2 kv-32 tiles × (K=64 as 4 slices of 16) ----
    f32x16 st[2];
    __builtin_amdgcn_s_setprio(1);
#pragma unroll
    for (int kvt = 0; kvt < 2; ++kvt) {
      const int row = kvt * 32 + ql;
      f32x16 a;
#pragma unroll
      for (int e = 0; e < 16; ++e) a[e] = 0.f;
#pragma unroll
      for (int dsl = 0; dsl < 4; ++dsl) {
        const int ch = dsl * 2 + hh;
        bf16x8 kf = *(const bf16x8*)&sKc[row * 64 + ((ch ^ (row & 7)) << 3)];
        a = __builtin_amdgcn_mfma_f32_32x32x16_bf16(kf, qf[dsl], a, 0, 0, 0);
      }
      st[kvt] = a;
    }
    __builtin_amdgcn_s_setprio(0);
    if (t == nt - 1) {  // diagonal tile: causal mask (within-tile indices)
#pragma unroll
      for (int kvt = 0; kvt < 2; ++kvt)
#pragma unroll
        for (int r = 0; r < 16; ++r) {
          const int kvl = kvt * 32 + (r & 3) + 8 * (r >> 2) + 4 * hh;
          if (kvl > w * 32 + ql) st[kvt][r] = -1e30f;
        }
    }
    // ---- fixed-max softmax + P^T packing (cvt_pk + permlane32_swap) ----
    bf16x8 pb[4];
#pragma unroll
    for (int kvt = 0; kvt < 2; ++kvt) {
      float p[16];
#pragma unroll
      for (int r = 0; r < 16; ++r) {
        p[r] = exp2f(st[kvt][r] - M);
        lsum += p[r];
      }
      unsigned int X[8];
#pragma unroll
      for (int i = 0; i < 8; ++i)
        asm("v_cvt_pk_bf16_f32 %0, %1, %2" : "=v"(X[i]) : "v"(p[2 * i]), "v"(p[2 * i + 1]));
      // swap(X0,X2),(X1,X3) -> words {0,2},{1,3} of pb[2kvt]; (X4,X6),(X5,X7) -> pb[2kvt+1]
      asm("v_permlane32_swap_b32 %0, %1" : "+v"(X[0]), "+v"(X[2]));
      asm("v_permlane32_swap_b32 %0, %1" : "+v"(X[1]), "+v"(X[3]));
      asm("v_permlane32_swap_b32 %0, %1" : "+v"(X[4]), "+v"(X[6]));
      asm("v_permlane32_swap_b32 %0, %1" : "+v"(X[5]), "+v"(X[7]));
      uint4v u0 = {X[0], X[1], X[2], X[3]};
      uint4v u1 = {X[4], X[5], X[6], X[7]};
      pb[2 * kvt]     = __builtin_bit_cast(bf16x8, u0);
      pb[2 * kvt + 1] = __builtin_bit_cast(bf16x8, u1);
    }
    // ---- PV: Y^T[d][q] += V^T * P^T ----
    __builtin_amdgcn_s_setprio(1);
#pragma unroll
    for (int ks = 0; ks < 4; ++ks) {
#pragma unroll
      for (int dt = 0; dt < 2; ++dt) {
        const int row = dt * 32 + ql;
        const int ch = ks * 2 + hh;
        bf16x8 vf = *(const bf16x8*)&sVc[row * 64 + ((ch ^ (row & 7)) << 3)];
        acc[dt] = __builtin_amdgcn_mfma_f32_32x32x16_bf16(vf, pb[ks], acc[dt], 0, 0, 0);
      }
    }
    __builtin_amdgcn_s_setprio(0);
    cur ^= 1;
  }
#undef STAGE_TILE
  lsum += __shfl_xor(lsum, 32);   // lanes l, l^32 hold complementary kv-rows of col ql
  const float inv = 1.0f / lsum;
  unsigned short* Y = yb + (size_t)(b * 2048 + q0 + ql) * 1024 + h * 64;
#pragma unroll
  for (int dt = 0; dt < 2; ++dt) {
#pragma unroll
    for (int rg = 0; rg < 4; ++rg) {
      ushort4v o;
#pragma unroll
      for (int j = 0; j < 4; ++j) o[j] = f2bf(acc[dt][rg * 4 + j] * inv);
      *(ushort4v*)(Y + dt * 32 + rg * 8 + hh * 4) = o;
    }
  }
}

extern "C" void kernel_launch(void* const* d_in, const int* in_sizes, int n_in,
                              void* d_out, int out_size, void* d_ws, size_t ws_size,
                              hipStream_t stream) {
  const float* x  = (const float*)d_in[0];
  const float* Wq = (const float*)d_in[1];
  const float* Wk = (const float*)d_in[2];
  const float* Wv = (const float*)d_in[3];
  const float* Wo = (const float*)d_in[4];
  const float* qg = (const float*)d_in[5];
  float* out = (float*)d_out;

  char* ws = (char*)d_ws;
  const size_t NEED = 47710208;
  if (ws_size < NEED) return;
  unsigned short* xb   = (unsigned short*)(ws);                 // 8,388,608
  unsigned short* wqkv = (unsigned short*)(ws + 8388608);       // 3,145,728
  unsigned short* wo_b = (unsigned short*)(ws + 11534336);      // 2,097,152
  unsigned short* qkvb = (unsigned short*)(ws + 13631488);      // 12,582,912 (bf16)
  unsigned short* qbuf = (unsigned short*)(ws + 26214400);      // 8,388,608
  unsigned short* kbuf = (unsigned short*)(ws + 34603008);      // 2,097,152
  unsigned short* vtb  = (unsigned short*)(ws + 36700160);      // 2,097,152
  unsigned short* ybuf = (unsigned short*)(ws + 38797312);      // 8,388,608
  float*          tab  = (float*)        (ws + 47185920);       // 524,288

  prep_kernel<<<6912, 256, 0, stream>>>(x, Wq, Wk, Wv, Wo, xb, wqkv, wo_b, tab);
  gemm_bt_kernel<true><<<64 * 12, 256, 0, stream>>>(xb, wqkv, qkvb, 4096, 1536, 1024, 12);
  pack_kernel<<<20480, 256, 0, stream>>>(qkvb, tab, qg, qbuf, kbuf);
  vpack_kernel<<<256, 256, 0, stream>>>(qkvb, vtb);
  attn_kernel<<<1024, 128, 0, stream>>>(qbuf, kbuf, vtb, ybuf, qg);
  gemm_bt_kernel<false><<<64 * 8, 256, 0, stream>>>(ybuf, wo_b, out, 4096, 1024, 1024, 8);
}

// Round 10
// 107.982 us; speedup vs baseline: 1.3027x; 1.3027x over previous
//
#include <hip/hip_runtime.h>
#include <hip/hip_bf16.h>
#include <math.h>

typedef __attribute__((ext_vector_type(8))) __bf16 bf16x8;
typedef __attribute__((ext_vector_type(4))) short short4v;
typedef __attribute__((ext_vector_type(4))) float f32x4;
typedef __attribute__((ext_vector_type(4))) unsigned short ushort4v;
typedef __attribute__((ext_vector_type(8))) unsigned short ushort8;

#define LOG2E 1.44269504088896340736f

static __device__ __forceinline__ unsigned short f2bf(float f) {
  unsigned int u = __float_as_uint(f);
  return (unsigned short)((u + 0x7fffu + ((u >> 16) & 1u)) >> 16);
}
static __device__ __forceinline__ short bfbits(float f) {
  __bf16 h = (__bf16)f;
  return __builtin_bit_cast(short, h);
}

static __device__ __forceinline__ void gload16(const unsigned short* g, void* l) {
  __builtin_amdgcn_global_load_lds(
      (const __attribute__((address_space(1))) unsigned int*)g,
      (__attribute__((address_space(3))) unsigned int*)l, 16, 0, 0);
}

// ---------------- fused prep: all casts + RoPE table ----------------
__global__ __launch_bounds__(256) void prep_kernel(
    const float* __restrict__ x, const float* __restrict__ Wq,
    const float* __restrict__ Wk, const float* __restrict__ Wv,
    const float* __restrict__ Wo,
    unsigned short* __restrict__ xb, unsigned short* __restrict__ wqkv,
    unsigned short* __restrict__ wo_b, float* __restrict__ tab) {
  const int bx = blockIdx.x, tid = threadIdx.x;
  if (bx < 6656) {
    const float* src;
    unsigned short* dst;
    int i;
    if (bx < 4096)       { src = x;  dst = xb;             i = bx * 256 + tid; }
    else if (bx < 5120)  { src = Wq; dst = wqkv;           i = (bx - 4096) * 256 + tid; }
    else if (bx < 5376)  { src = Wk; dst = wqkv + 1048576; i = (bx - 5120) * 256 + tid; }
    else if (bx < 5632)  { src = Wv; dst = wqkv + 1310720; i = (bx - 5376) * 256 + tid; }
    else                 { src = Wo; dst = wo_b;           i = (bx - 5632) * 256 + tid; }
    float4 v = reinterpret_cast<const float4*>(src)[i];
    ushort4v o;
    o.x = f2bf(v.x); o.y = f2bf(v.y); o.z = f2bf(v.z); o.w = f2bf(v.w);
    reinterpret_cast<ushort4v*>(dst)[i] = o;
  } else {
    int i = (bx - 6656) * 256 + tid;  // 65536 = 2048*32
    int s = i >> 5, d = i & 31;
    float invf = powf(10000.f, -(float)d / 32.f);
    float fr = (float)s * invf;
    tab[s * 64 + d] = cosf(fr);
    tab[s * 64 + 32 + d] = sinf(fr);
  }
}

// ---------------- fused QKV GEMM: qkv = x @ Wqkv^T with RMSNorm/RoPE/pack epilogue ----
// BM=64, BN=128, BK=64; 4 waves (2x2), wave tile 32x64 = acc[2][4].
// A wave's 64-col span is exactly one head. For fixed (m,j), the 16 lr-lanes x 4 n-frags
// hold all 64 dims of one row: RMSNorm reduces over lr (xor 1/2/4/8); RoPE pairs
// (d, d+32) = (n, n+2) are in-lane. Q scaled by qg*0.125*log2(e).
__global__ __launch_bounds__(256) void gemm_qkv_kernel(
    const unsigned short* __restrict__ A, const unsigned short* __restrict__ B,
    const float* __restrict__ tab, const float* __restrict__ qg,
    unsigned short* __restrict__ qb, unsigned short* __restrict__ kb,
    unsigned short* __restrict__ vsl) {
  __shared__ unsigned short sA[64 * 64];
  __shared__ unsigned short sB[128 * 64];
  const int t = threadIdx.x;
  const int lane = t & 63;
  const int w = t >> 6;
  const int bm = blockIdx.x / 12, bn = blockIdx.x % 12;
  const long m0 = (long)bm * 64, n0 = (long)bn * 128;
  const int wm = (w >> 1) * 32, wn = (w & 1) * 64;
  const int lr = lane & 15, lg = lane >> 4;
  f32x4 acc[2][4];
#pragma unroll
  for (int i = 0; i < 2; i++)
#pragma unroll
    for (int j = 0; j < 4; j++) acc[i][j] = (f32x4){0.f, 0.f, 0.f, 0.f};

  for (int k0 = 0; k0 < 1024; k0 += 64) {
#pragma unroll
    for (int i = 0; i < 2; i++) {
      int chunk = i * 256 + t;
      int r = chunk >> 3;
      int c = (chunk & 7) << 3;
      gload16(A + (m0 + r) * 1024 + k0 + c, (char*)sA + chunk * 16);
    }
#pragma unroll
    for (int i = 0; i < 4; i++) {
      int chunk = i * 256 + t;
      int r = chunk >> 3;
      int c = (chunk & 7) << 3;
      gload16(B + (n0 + r) * 1024 + k0 + c, (char*)sB + chunk * 16);
    }
    __syncthreads();
#pragma unroll
    for (int kk = 0; kk < 2; ++kk) {
      bf16x8 af[2], bfr[4];
#pragma unroll
      for (int m = 0; m < 2; m++)
        af[m] = *(const bf16x8*)&sA[(wm + m * 16 + lr) * 64 + kk * 32 + lg * 8];
#pragma unroll
      for (int n = 0; n < 4; n++)
        bfr[n] = *(const bf16x8*)&sB[(wn + n * 16 + lr) * 64 + kk * 32 + lg * 8];
#pragma unroll
      for (int m = 0; m < 2; m++)
#pragma unroll
        for (int n = 0; n < 4; n++)
          acc[m][n] = __builtin_amdgcn_mfma_f32_16x16x32_bf16(af[m], bfr[n], acc[m][n], 0, 0, 0);
    }
    __syncthreads();
  }
  // ---- fused epilogue ----
  const int bb = (int)(m0 >> 11);          // batch (64-row tile never straddles b)
  const int s_base = (int)(m0 & 2047) + wm + lg * 4;
  const int hsel = wn >> 6;                // which head of the 128-col block
  if (bn < 10) {
    // Q (bn<8) or K (bn 8,9): RMSNorm + RoPE (+gain for Q) -> bf16
    float gscale = 1.0f;
    unsigned short* dstb;
    if (bn < 8) {
      gscale = qg[2 * bn + hsel] * (0.125f * LOG2E);
      dstb = qb + (size_t)(bb * 16 + 2 * bn + hsel) * 2048 * 64;
    } else {
      dstb = kb + (size_t)(bb * 4 + 2 * (bn - 8) + hsel) * 2048 * 64;
    }
#pragma unroll
    for (int m = 0; m < 2; m++) {
#pragma unroll
      for (int j = 0; j < 4; j++) {
        float ss = acc[m][0][j] * acc[m][0][j] + acc[m][1][j] * acc[m][1][j] +
                   acc[m][2][j] * acc[m][2][j] + acc[m][3][j] * acc[m][3][j];
        ss += __shfl_xor(ss, 1);
        ss += __shfl_xor(ss, 2);
        ss += __shfl_xor(ss, 4);
        ss += __shfl_xor(ss, 8);
        const float rinv = rsqrtf(ss * (1.0f / 64.0f) + 1.1920929e-07f);
        const int s = s_base + m * 16 + j;
        const float* tr = tab + s * 64;
        const float c0 = tr[lr], c1 = tr[16 + lr];
        const float s0 = tr[32 + lr], s1 = tr[48 + lr];
        const float n0v = acc[m][0][j] * rinv, n1v = acc[m][1][j] * rinv;
        const float n2v = acc[m][2][j] * rinv, n3v = acc[m][3][j] * rinv;
        float o0 = (n0v * c0 + n2v * s0) * gscale;
        float o1 = (n1v * c1 + n3v * s1) * gscale;
        float o2 = (n2v * c0 - n0v * s0) * gscale;
        float o3 = (n3v * c1 - n1v * s1) * gscale;
        unsigned short* d = dstb + (size_t)s * 64;
        d[lr]      = f2bf(o0);
        d[16 + lr] = f2bf(o1);
        d[32 + lr] = f2bf(o2);
        d[48 + lr] = f2bf(o3);
      }
    }
  } else {
    // V (bn 10,11): plain bf16 to compact slice vsl[b*2048+s][256]
#pragma unroll
    for (int m = 0; m < 2; m++) {
#pragma unroll
      for (int j = 0; j < 4; j++) {
        const int s = s_base + m * 16 + j;
        unsigned short* d = vsl + (size_t)(bb * 2048 + s) * 256 + (bn - 10) * 128 + wn;
#pragma unroll
        for (int n = 0; n < 4; n++) d[n * 16 + lr] = f2bf(acc[m][n][j]);
      }
    }
  }
}

// ---------------- bf16 GEMM: C[M,N] f32 = A[M,K] * B[N,K]^T (out proj) ----------------
__global__ __launch_bounds__(256) void gemm_bt_kernel(
    const unsigned short* __restrict__ A, const unsigned short* __restrict__ B,
    float* __restrict__ C, int M, int N, int K, int nbn) {
  __shared__ unsigned short sA[64 * 64];
  __shared__ unsigned short sB[128 * 64];
  const int t = threadIdx.x;
  const int lane = t & 63;
  const int w = t >> 6;
  const int bm = blockIdx.x / nbn, bn = blockIdx.x % nbn;
  const long m0 = (long)bm * 64, n0 = (long)bn * 128;
  const int wm = (w >> 1) * 32, wn = (w & 1) * 64;
  const int lr = lane & 15, lg = lane >> 4;
  f32x4 acc[2][4];
#pragma unroll
  for (int i = 0; i < 2; i++)
#pragma unroll
    for (int j = 0; j < 4; j++) acc[i][j] = (f32x4){0.f, 0.f, 0.f, 0.f};

  for (int k0 = 0; k0 < K; k0 += 64) {
#pragma unroll
    for (int i = 0; i < 2; i++) {
      int chunk = i * 256 + t;
      int r = chunk >> 3;
      int c = (chunk & 7) << 3;
      gload16(A + (m0 + r) * (long)K + k0 + c, (char*)sA + chunk * 16);
    }
#pragma unroll
    for (int i = 0; i < 4; i++) {
      int chunk = i * 256 + t;
      int r = chunk >> 3;
      int c = (chunk & 7) << 3;
      gload16(B + (n0 + r) * (long)K + k0 + c, (char*)sB + chunk * 16);
    }
    __syncthreads();
#pragma unroll
    for (int kk = 0; kk < 2; ++kk) {
      bf16x8 af[2], bfr[4];
#pragma unroll
      for (int m = 0; m < 2; m++)
        af[m] = *(const bf16x8*)&sA[(wm + m * 16 + lr) * 64 + kk * 32 + lg * 8];
#pragma unroll
      for (int n = 0; n < 4; n++)
        bfr[n] = *(const bf16x8*)&sB[(wn + n * 16 + lr) * 64 + kk * 32 + lg * 8];
#pragma unroll
      for (int m = 0; m < 2; m++)
#pragma unroll
        for (int n = 0; n < 4; n++)
          acc[m][n] = __builtin_amdgcn_mfma_f32_16x16x32_bf16(af[m], bfr[n], acc[m][n], 0, 0, 0);
    }
    __syncthreads();
  }
#pragma unroll
  for (int m = 0; m < 2; m++) {
#pragma unroll
    for (int n = 0; n < 4; n++) {
      long col = n0 + wn + n * 16 + lr;
#pragma unroll
      for (int j = 0; j < 4; j++) {
        long row = m0 + wm + m * 16 + lg * 4 + j;
        C[row * N + col] = acc[m][n][j];
      }
    }
  }
}

// ---------------- V transpose: vsl [s][hk*64+d] -> vtb [d][s] ----------------
__global__ __launch_bounds__(256) void vpack_kernel(
    const unsigned short* __restrict__ vsl, unsigned short* __restrict__ vtb) {
  __shared__ unsigned short sT[64 * 65];
  const int tid = threadIdx.x;
  const int bhk = blockIdx.x >> 5;          // 0..7 = b*4+hk
  const int st = blockIdx.x & 31;           // s-tile
  const int b = bhk >> 2, hk = bhk & 3;
  const int r = tid >> 2, cg = (tid & 3) << 4;
  const unsigned short* src = vsl + (size_t)(b * 2048 + st * 64 + r) * 256 + hk * 64 + cg;
  ushort8 v0 = *(const ushort8*)src;
  ushort8 v1 = *(const ushort8*)(src + 8);
#pragma unroll
  for (int k = 0; k < 8; ++k) sT[r * 65 + cg + k] = v0[k];
#pragma unroll
  for (int k = 0; k < 8; ++k) sT[r * 65 + cg + 8 + k] = v1[k];
  __syncthreads();
  const int d = tid >> 2, sg = (tid & 3) << 4;
  ushort8 o0, o1;
#pragma unroll
  for (int k = 0; k < 8; ++k) o0[k] = sT[(sg + k) * 65 + d];
#pragma unroll
  for (int k = 0; k < 8; ++k) o1[k] = sT[(sg + 8 + k) * 65 + d];
  unsigned short* dst = vtb + ((size_t)(bhk * 64 + d)) * 2048 + st * 64 + sg;
  *(ushort8*)dst = o0;
  *(ushort8*)(dst + 8) = o1;
}

// ---------------- causal flash attention (measured-best structure, R5/R6) ----------------
// 4 waves / 256 threads; block = 64 q rows of one (b,h); KVBLK=64, double-buffered LDS.
// Fixed-max softmax (M = 11.7*|g|); heavy-first dispatch; hoisted staging pointers.
__global__ __launch_bounds__(256) void attn_kernel(
    const unsigned short* __restrict__ qb, const unsigned short* __restrict__ kb,
    const unsigned short* __restrict__ vtb, unsigned short* __restrict__ yb,
    const float* __restrict__ qg) {
  __shared__ unsigned short sK[2][64 * 64];
  __shared__ unsigned short sV[2][64 * 64];
  const int tid = threadIdx.x;
  const int lane = tid & 63;
  const int w = tid >> 6;
  const int qt = 31 - (blockIdx.x >> 5);   // heavy-first
  const int bh = blockIdx.x & 31;
  const int h = bh & 15;
  const int b = bh >> 4;
  const float M = 11.7f * fabsf(qg[h]);
  const int q0 = qt * 64 + w * 16;
  const unsigned short* Q  = qb  + (size_t)(b * 16 + h) * 2048 * 64;
  const unsigned short* Kp = kb  + (size_t)(b * 4 + (h >> 2)) * 2048 * 64;
  const unsigned short* Vp = vtb + (size_t)(b * 4 + (h >> 2)) * 64 * 2048;
  const int qc = lane & 15;
  const int g = lane >> 4;
  const int qrow = q0 + qc;
  const bf16x8 qf0 = *(const bf16x8*)(Q + (size_t)qrow * 64 + g * 8);
  const bf16x8 qf1 = *(const bf16x8*)(Q + (size_t)qrow * 64 + 32 + g * 8);
  f32x4 acc[4];
  acc[0] = acc[1] = acc[2] = acc[3] = (f32x4){0.f, 0.f, 0.f, 0.f};
  float lsum = 0.f;
  const int nt = qt + 1;

  // hoisted staging pointers: 2 K-chunks + 2 V-chunks per thread
  const int r0 = tid >> 3, c0 = tid & 7;
  const int swz = ((c0 ^ (r0 & 7)) << 3);
  const unsigned short* gK = Kp + (size_t)r0 * 64 + swz;
  const unsigned short* gV = Vp + (size_t)r0 * 2048 + swz;

  gload16(gK,             (char*)&sK[0][0] + tid * 16);
  gload16(gK + 32 * 64,   (char*)&sK[0][0] + (tid + 256) * 16);
  gload16(gV,             (char*)&sV[0][0] + tid * 16);
  gload16(gV + 32 * 2048, (char*)&sV[0][0] + (tid + 256) * 16);
  gK += 64 * 64; gV += 64;

  int cur = 0;
  for (int t = 0; t < nt; ++t) {
    __syncthreads();   // drains vmcnt: buf[cur] staged; buf[cur^1] free
    if (t + 1 < nt) {  // prefetch next tile
      const int nb = cur ^ 1;
      gload16(gK,             (char*)&sK[nb][0] + tid * 16);
      gload16(gK + 32 * 64,   (char*)&sK[nb][0] + (tid + 256) * 16);
      gload16(gV,             (char*)&sV[nb][0] + tid * 16);
      gload16(gV + 32 * 2048, (char*)&sV[nb][0] + (tid + 256) * 16);
      gK += 64 * 64; gV += 64;
    }
    const unsigned short* sKc = &sK[cur][0];
    const unsigned short* sVc = &sV[cur][0];
    // ---- QK^T ----
    f32x4 st[4];
    __builtin_amdgcn_s_setprio(1);
#pragma unroll
    for (int ks = 0; ks < 4; ++ks) {
      const int rr = ks * 16 + qc;
      bf16x8 kf0 = *(const bf16x8*)&sKc[rr * 64 + ((g ^ (rr & 7)) << 3)];
      bf16x8 kf1 = *(const bf16x8*)&sKc[rr * 64 + (((4 + g) ^ (rr & 7)) << 3)];
      f32x4 a = (f32x4){0.f, 0.f, 0.f, 0.f};
      a = __builtin_amdgcn_mfma_f32_16x16x32_bf16(kf0, qf0, a, 0, 0, 0);
      a = __builtin_amdgcn_mfma_f32_16x16x32_bf16(kf1, qf1, a, 0, 0, 0);
      st[ks] = a;
    }
    __builtin_amdgcn_s_setprio(0);
    if (t == nt - 1) {  // diagonal tile: within-tile causal mask
#pragma unroll
      for (int ks = 0; ks < 4; ++ks)
#pragma unroll
        for (int j = 0; j < 4; ++j)
          if (ks * 16 + g * 4 + j > w * 16 + qc) st[ks][j] = -1e30f;
    }
    // ---- fixed-max softmax: p = exp2(s - M) ----
    short4v pb[4];
#pragma unroll
    for (int ks = 0; ks < 4; ++ks)
#pragma unroll
      for (int j = 0; j < 4; ++j) {
        float p = exp2f(st[ks][j] - M);
        lsum += p;
        pb[ks][j] = bfbits(p);
      }
    // ---- PV: Y^T += V^T * P^T ----
    __builtin_amdgcn_s_setprio(1);
#pragma unroll
    for (int ks = 0; ks < 4; ++ks) {
#pragma unroll
      for (int d = 0; d < 4; ++d) {
        const int rd = d * 16 + qc;
        const int el = rd * 64 + ((((ks * 2 + (g >> 1)) ^ (rd & 7)) << 3) + ((g & 1) << 2));
        short4v vf = *(const short4v*)&sVc[el];
        acc[d] = __builtin_amdgcn_mfma_f32_16x16x16bf16_1k(vf, pb[ks], acc[d], 0, 0, 0);
      }
    }
    __builtin_amdgcn_s_setprio(0);
    cur ^= 1;
  }
  float l = lsum;
  l += __shfl_xor(l, 16);
  l += __shfl_xor(l, 32);
  const float inv = 1.0f / l;
  unsigned short* Y = yb + (size_t)(b * 2048 + qrow) * 1024 + h * 64;
#pragma unroll
  for (int d = 0; d < 4; ++d)
#pragma unroll
    for (int j = 0; j < 4; ++j)
      Y[d * 16 + g * 4 + j] = (unsigned short)bfbits(acc[d][j] * inv);
}

extern "C" void kernel_launch(void* const* d_in, const int* in_sizes, int n_in,
                              void* d_out, int out_size, void* d_ws, size_t ws_size,
                              hipStream_t stream) {
  const float* x  = (const float*)d_in[0];
  const float* Wq = (const float*)d_in[1];
  const float* Wk = (const float*)d_in[2];
  const float* Wv = (const float*)d_in[3];
  const float* Wo = (const float*)d_in[4];
  const float* qg = (const float*)d_in[5];
  float* out = (float*)d_out;

  char* ws = (char*)d_ws;
  const size_t NEED = 37224448;
  if (ws_size < NEED) return;
  unsigned short* xb   = (unsigned short*)(ws);                 // 8,388,608
  unsigned short* wqkv = (unsigned short*)(ws + 8388608);       // 3,145,728
  unsigned short* wo_b = (unsigned short*)(ws + 11534336);      // 2,097,152
  unsigned short* vsl  = (unsigned short*)(ws + 13631488);      // 2,097,152
  unsigned short* qbuf = (unsigned short*)(ws + 15728640);      // 8,388,608
  unsigned short* kbuf = (unsigned short*)(ws + 24117248);      // 2,097,152
  unsigned short* vtb  = (unsigned short*)(ws + 26214400);      // 2,097,152
  unsigned short* ybuf = (unsigned short*)(ws + 28311552);      // 8,388,608
  float*          tab  = (float*)        (ws + 36700160);       // 524,288

  prep_kernel<<<6912, 256, 0, stream>>>(x, Wq, Wk, Wv, Wo, xb, wqkv, wo_b, tab);
  gemm_qkv_kernel<<<64 * 12, 256, 0, stream>>>(xb, wqkv, tab, qg, qbuf, kbuf, vsl);
  vpack_kernel<<<256, 256, 0, stream>>>(vsl, vtb);
  attn_kernel<<<1024, 256, 0, stream>>>(qbuf, kbuf, vtb, ybuf, qg);
  gemm_bt_kernel<<<64 * 8, 256, 0, stream>>>(ybuf, wo_b, out, 4096, 1024, 1024, 8);
}

// Round 11
// 105.297 us; speedup vs baseline: 1.3359x; 1.0255x over previous
//
#include <hip/hip_runtime.h>
#include <hip/hip_bf16.h>
#include <math.h>

typedef __attribute__((ext_vector_type(8))) __bf16 bf16x8;
typedef __attribute__((ext_vector_type(4))) short short4v;
typedef __attribute__((ext_vector_type(4))) float f32x4;
typedef __attribute__((ext_vector_type(4))) unsigned short ushort4v;
typedef __attribute__((ext_vector_type(8))) unsigned short ushort8;

#define LOG2E 1.44269504088896340736f

static __device__ __forceinline__ unsigned short f2bf(float f) {
  unsigned int u = __float_as_uint(f);
  return (unsigned short)((u + 0x7fffu + ((u >> 16) & 1u)) >> 16);
}
static __device__ __forceinline__ short bfbits(float f) {
  __bf16 h = (__bf16)f;
  return __builtin_bit_cast(short, h);
}

static __device__ __forceinline__ void gload16(const unsigned short* g, void* l) {
  __builtin_amdgcn_global_load_lds(
      (const __attribute__((address_space(1))) unsigned int*)g,
      (__attribute__((address_space(3))) unsigned int*)l, 16, 0, 0);
}

// ---------------- fused prep: all casts + RoPE table ----------------
__global__ __launch_bounds__(256) void prep_kernel(
    const float* __restrict__ x, const float* __restrict__ Wq,
    const float* __restrict__ Wk, const float* __restrict__ Wv,
    const float* __restrict__ Wo,
    unsigned short* __restrict__ xb, unsigned short* __restrict__ wqkv,
    unsigned short* __restrict__ wo_b, float* __restrict__ tab) {
  const int bx = blockIdx.x, tid = threadIdx.x;
  if (bx < 6656) {
    const float* src;
    unsigned short* dst;
    int i;
    if (bx < 4096)       { src = x;  dst = xb;             i = bx * 256 + tid; }
    else if (bx < 5120)  { src = Wq; dst = wqkv;           i = (bx - 4096) * 256 + tid; }
    else if (bx < 5376)  { src = Wk; dst = wqkv + 1048576; i = (bx - 5120) * 256 + tid; }
    else if (bx < 5632)  { src = Wv; dst = wqkv + 1310720; i = (bx - 5376) * 256 + tid; }
    else                 { src = Wo; dst = wo_b;           i = (bx - 5632) * 256 + tid; }
    float4 v = reinterpret_cast<const float4*>(src)[i];
    ushort4v o;
    o.x = f2bf(v.x); o.y = f2bf(v.y); o.z = f2bf(v.z); o.w = f2bf(v.w);
    reinterpret_cast<ushort4v*>(dst)[i] = o;
  } else {
    int i = (bx - 6656) * 256 + tid;  // 65536 = 2048*32
    int s = i >> 5, d = i & 31;
    float invf = powf(10000.f, -(float)d / 32.f);
    float fr = (float)s * invf;
    tab[s * 64 + d] = cosf(fr);
    tab[s * 64 + 32 + d] = sinf(fr);
  }
}

// ---------------- fused QKV GEMM: qkv = x @ Wqkv^T + RMSNorm/RoPE/pack epilogue ----
// BM=64, BN=128, BK=64; 4 waves (2x2), wave tile 32x64 = acc[2][4].
// Q/K (bn<10): RMSNorm (xor 1/2/4/8 over lr) + RoPE (in-lane pairs n,n+2) + gain -> bf16.
// V (bn 10,11): bf16 + in-LDS transpose (reusing the staging LDS) -> vtb[d][s] directly.
__global__ __launch_bounds__(256) void gemm_qkv_kernel(
    const unsigned short* __restrict__ A, const unsigned short* __restrict__ B,
    const float* __restrict__ tab, const float* __restrict__ qg,
    unsigned short* __restrict__ qb, unsigned short* __restrict__ kb,
    unsigned short* __restrict__ vtb) {
  __shared__ unsigned short sAll[64 * 64 + 128 * 64];
  unsigned short* sA = sAll;
  unsigned short* sB = sAll + 64 * 64;
  const int t = threadIdx.x;
  const int lane = t & 63;
  const int w = t >> 6;
  const int bm = blockIdx.x / 12, bn = blockIdx.x % 12;
  const long m0 = (long)bm * 64, n0 = (long)bn * 128;
  const int wm = (w >> 1) * 32, wn = (w & 1) * 64;
  const int lr = lane & 15, lg = lane >> 4;
  f32x4 acc[2][4];
#pragma unroll
  for (int i = 0; i < 2; i++)
#pragma unroll
    for (int j = 0; j < 4; j++) acc[i][j] = (f32x4){0.f, 0.f, 0.f, 0.f};

  for (int k0 = 0; k0 < 1024; k0 += 64) {
#pragma unroll
    for (int i = 0; i < 2; i++) {
      int chunk = i * 256 + t;
      int r = chunk >> 3;
      int c = (chunk & 7) << 3;
      gload16(A + (m0 + r) * 1024 + k0 + c, (char*)sA + chunk * 16);
    }
#pragma unroll
    for (int i = 0; i < 4; i++) {
      int chunk = i * 256 + t;
      int r = chunk >> 3;
      int c = (chunk & 7) << 3;
      gload16(B + (n0 + r) * 1024 + k0 + c, (char*)sB + chunk * 16);
    }
    __syncthreads();
#pragma unroll
    for (int kk = 0; kk < 2; ++kk) {
      bf16x8 af[2], bfr[4];
#pragma unroll
      for (int m = 0; m < 2; m++)
        af[m] = *(const bf16x8*)&sA[(wm + m * 16 + lr) * 64 + kk * 32 + lg * 8];
#pragma unroll
      for (int n = 0; n < 4; n++)
        bfr[n] = *(const bf16x8*)&sB[(wn + n * 16 + lr) * 64 + kk * 32 + lg * 8];
#pragma unroll
      for (int m = 0; m < 2; m++)
#pragma unroll
        for (int n = 0; n < 4; n++)
          acc[m][n] = __builtin_amdgcn_mfma_f32_16x16x32_bf16(af[m], bfr[n], acc[m][n], 0, 0, 0);
    }
    __syncthreads();
  }
  // ---- fused epilogue ----
  const int bb = (int)(m0 >> 11);          // batch (64-row tile never straddles b)
  const int s_base = (int)(m0 & 2047) + wm + lg * 4;
  const int hsel = wn >> 6;                // which head of the 128-col block
  if (bn < 10) {
    // Q (bn<8) or K (bn 8,9): RMSNorm + RoPE (+gain for Q) -> bf16
    float gscale = 1.0f;
    unsigned short* dstb;
    if (bn < 8) {
      gscale = qg[2 * bn + hsel] * (0.125f * LOG2E);
      dstb = qb + (size_t)(bb * 16 + 2 * bn + hsel) * 2048 * 64;
    } else {
      dstb = kb + (size_t)(bb * 4 + 2 * (bn - 8) + hsel) * 2048 * 64;
    }
#pragma unroll
    for (int m = 0; m < 2; m++) {
#pragma unroll
      for (int j = 0; j < 4; j++) {
        float ss = acc[m][0][j] * acc[m][0][j] + acc[m][1][j] * acc[m][1][j] +
                   acc[m][2][j] * acc[m][2][j] + acc[m][3][j] * acc[m][3][j];
        ss += __shfl_xor(ss, 1);
        ss += __shfl_xor(ss, 2);
        ss += __shfl_xor(ss, 4);
        ss += __shfl_xor(ss, 8);
        const float rinv = rsqrtf(ss * (1.0f / 64.0f) + 1.1920929e-07f);
        const int s = s_base + m * 16 + j;
        const float* tr = tab + s * 64;
        const float c0 = tr[lr], c1 = tr[16 + lr];
        const float s0 = tr[32 + lr], s1 = tr[48 + lr];
        const float n0v = acc[m][0][j] * rinv, n1v = acc[m][1][j] * rinv;
        const float n2v = acc[m][2][j] * rinv, n3v = acc[m][3][j] * rinv;
        float o0 = (n0v * c0 + n2v * s0) * gscale;
        float o1 = (n1v * c1 + n3v * s1) * gscale;
        float o2 = (n2v * c0 - n0v * s0) * gscale;
        float o3 = (n3v * c1 - n1v * s1) * gscale;
        unsigned short* d = dstb + (size_t)s * 64;
        d[lr]      = f2bf(o0);
        d[16 + lr] = f2bf(o1);
        d[32 + lr] = f2bf(o2);
        d[48 + lr] = f2bf(o3);
      }
    }
  } else {
    // V (bn 10,11): bf16 + transpose via LDS [2 heads][64 s][72 pad] -> vtb [d][s]
    unsigned short* sT = sAll;
#pragma unroll
    for (int m = 0; m < 2; m++)
#pragma unroll
      for (int j = 0; j < 4; j++) {
        const int srow = wm + m * 16 + lg * 4 + j;
#pragma unroll
        for (int n = 0; n < 4; n++)
          sT[(hsel * 64 + srow) * 72 + n * 16 + lr] = f2bf(acc[m][n][j]);
      }
    __syncthreads();
    const int hd = t >> 7;                 // head within block: 0/1
    const int d  = (t >> 1) & 63;
    const int sh = t & 1;                  // s-half: 0/1
    const int hk = 2 * (bn - 10) + hd;
    unsigned short* dst = vtb + ((size_t)((bb * 4 + hk) * 64 + d)) * 2048 +
                          (int)(m0 & 2047) + sh * 32;
    ushort8 o;
#pragma unroll
    for (int c = 0; c < 4; ++c) {
#pragma unroll
      for (int k = 0; k < 8; ++k) o[k] = sT[(hd * 64 + sh * 32 + c * 8 + k) * 72 + d];
      *(ushort8*)(dst + c * 8) = o;
    }
  }
}

// ---------------- bf16 GEMM: C[M,N] f32 = A[M,K] * B[N,K]^T (out proj) ----------------
__global__ __launch_bounds__(256) void gemm_bt_kernel(
    const unsigned short* __restrict__ A, const unsigned short* __restrict__ B,
    float* __restrict__ C, int M, int N, int K, int nbn) {
  __shared__ unsigned short sA[64 * 64];
  __shared__ unsigned short sB[128 * 64];
  const int t = threadIdx.x;
  const int lane = t & 63;
  const int w = t >> 6;
  const int bm = blockIdx.x / nbn, bn = blockIdx.x % nbn;
  const long m0 = (long)bm * 64, n0 = (long)bn * 128;
  const int wm = (w >> 1) * 32, wn = (w & 1) * 64;
  const int lr = lane & 15, lg = lane >> 4;
  f32x4 acc[2][4];
#pragma unroll
  for (int i = 0; i < 2; i++)
#pragma unroll
    for (int j = 0; j < 4; j++) acc[i][j] = (f32x4){0.f, 0.f, 0.f, 0.f};

  for (int k0 = 0; k0 < K; k0 += 64) {
#pragma unroll
    for (int i = 0; i < 2; i++) {
      int chunk = i * 256 + t;
      int r = chunk >> 3;
      int c = (chunk & 7) << 3;
      gload16(A + (m0 + r) * (long)K + k0 + c, (char*)sA + chunk * 16);
    }
#pragma unroll
    for (int i = 0; i < 4; i++) {
      int chunk = i * 256 + t;
      int r = chunk >> 3;
      int c = (chunk & 7) << 3;
      gload16(B + (n0 + r) * (long)K + k0 + c, (char*)sB + chunk * 16);
    }
    __syncthreads();
#pragma unroll
    for (int kk = 0; kk < 2; ++kk) {
      bf16x8 af[2], bfr[4];
#pragma unroll
      for (int m = 0; m < 2; m++)
        af[m] = *(const bf16x8*)&sA[(wm + m * 16 + lr) * 64 + kk * 32 + lg * 8];
#pragma unroll
      for (int n = 0; n < 4; n++)
        bfr[n] = *(const bf16x8*)&sB[(wn + n * 16 + lr) * 64 + kk * 32 + lg * 8];
#pragma unroll
      for (int m = 0; m < 2; m++)
#pragma unroll
        for (int n = 0; n < 4; n++)
          acc[m][n] = __builtin_amdgcn_mfma_f32_16x16x32_bf16(af[m], bfr[n], acc[m][n], 0, 0, 0);
    }
    __syncthreads();
  }
#pragma unroll
  for (int m = 0; m < 2; m++) {
#pragma unroll
    for (int n = 0; n < 4; n++) {
      long col = n0 + wn + n * 16 + lr;
#pragma unroll
      for (int j = 0; j < 4; j++) {
        long row = m0 + wm + m * 16 + lg * 4 + j;
        C[row * N + col] = acc[m][n][j];
      }
    }
  }
}

// ---------------- causal flash attention (measured-best structure, R5/R6) ----------------
// 4 waves / 256 threads; block = 64 q rows of one (b,h); KVBLK=64, double-buffered LDS.
// Fixed-max softmax (M = 11.7*|g|); heavy-first dispatch; hoisted staging pointers.
__global__ __launch_bounds__(256) void attn_kernel(
    const unsigned short* __restrict__ qb, const unsigned short* __restrict__ kb,
    const unsigned short* __restrict__ vtb, unsigned short* __restrict__ yb,
    const float* __restrict__ qg) {
  __shared__ unsigned short sK[2][64 * 64];
  __shared__ unsigned short sV[2][64 * 64];
  const int tid = threadIdx.x;
  const int lane = tid & 63;
  const int w = tid >> 6;
  const int qt = 31 - (blockIdx.x >> 5);   // heavy-first
  const int bh = blockIdx.x & 31;
  const int h = bh & 15;
  const int b = bh >> 4;
  const float M = 11.7f * fabsf(qg[h]);
  const int q0 = qt * 64 + w * 16;
  const unsigned short* Q  = qb  + (size_t)(b * 16 + h) * 2048 * 64;
  const unsigned short* Kp = kb  + (size_t)(b * 4 + (h >> 2)) * 2048 * 64;
  const unsigned short* Vp = vtb + (size_t)(b * 4 + (h >> 2)) * 64 * 2048;
  const int qc = lane & 15;
  const int g = lane >> 4;
  const int qrow = q0 + qc;
  const bf16x8 qf0 = *(const bf16x8*)(Q + (size_t)qrow * 64 + g * 8);
  const bf16x8 qf1 = *(const bf16x8*)(Q + (size_t)qrow * 64 + 32 + g * 8);
  f32x4 acc[4];
  acc[0] = acc[1] = acc[2] = acc[3] = (f32x4){0.f, 0.f, 0.f, 0.f};
  float lsum = 0.f;
  const int nt = qt + 1;

  // hoisted staging pointers: 2 K-chunks + 2 V-chunks per thread
  const int r0 = tid >> 3, c0 = tid & 7;
  const int swz = ((c0 ^ (r0 & 7)) << 3);
  const unsigned short* gK = Kp + (size_t)r0 * 64 + swz;
  const unsigned short* gV = Vp + (size_t)r0 * 2048 + swz;

  gload16(gK,             (char*)&sK[0][0] + tid * 16);
  gload16(gK + 32 * 64,   (char*)&sK[0][0] + (tid + 256) * 16);
  gload16(gV,             (char*)&sV[0][0] + tid * 16);
  gload16(gV + 32 * 2048, (char*)&sV[0][0] + (tid + 256) * 16);
  gK += 64 * 64; gV += 64;

  int cur = 0;
  for (int t = 0; t < nt; ++t) {
    __syncthreads();   // drains vmcnt: buf[cur] staged; buf[cur^1] free
    if (t + 1 < nt) {  // prefetch next tile
      const int nb = cur ^ 1;
      gload16(gK,             (char*)&sK[nb][0] + tid * 16);
      gload16(gK + 32 * 64,   (char*)&sK[nb][0] + (tid + 256) * 16);
      gload16(gV,             (char*)&sV[nb][0] + tid * 16);
      gload16(gV + 32 * 2048, (char*)&sV[nb][0] + (tid + 256) * 16);
      gK += 64 * 64; gV += 64;
    }
    const unsigned short* sKc = &sK[cur][0];
    const unsigned short* sVc = &sV[cur][0];
    // ---- QK^T ----
    f32x4 st[4];
    __builtin_amdgcn_s_setprio(1);
#pragma unroll
    for (int ks = 0; ks < 4; ++ks) {
      const int rr = ks * 16 + qc;
      bf16x8 kf0 = *(const bf16x8*)&sKc[rr * 64 + ((g ^ (rr & 7)) << 3)];
      bf16x8 kf1 = *(const bf16x8*)&sKc[rr * 64 + (((4 + g) ^ (rr & 7)) << 3)];
      f32x4 a = (f32x4){0.f, 0.f, 0.f, 0.f};
      a = __builtin_amdgcn_mfma_f32_16x16x32_bf16(kf0, qf0, a, 0, 0, 0);
      a = __builtin_amdgcn_mfma_f32_16x16x32_bf16(kf1, qf1, a, 0, 0, 0);
      st[ks] = a;
    }
    __builtin_amdgcn_s_setprio(0);
    if (t == nt - 1) {  // diagonal tile: within-tile causal mask
#pragma unroll
      for (int ks = 0; ks < 4; ++ks)
#pragma unroll
        for (int j = 0; j < 4; ++j)
          if (ks * 16 + g * 4 + j > w * 16 + qc) st[ks][j] = -1e30f;
    }
    // ---- fixed-max softmax: p = exp2(s - M) ----
    short4v pb[4];
#pragma unroll
    for (int ks = 0; ks < 4; ++ks)
#pragma unroll
      for (int j = 0; j < 4; ++j) {
        float p = exp2f(st[ks][j] - M);
        lsum += p;
        pb[ks][j] = bfbits(p);
      }
    // ---- PV: Y^T += V^T * P^T ----
    __builtin_amdgcn_s_setprio(1);
#pragma unroll
    for (int ks = 0; ks < 4; ++ks) {
#pragma unroll
      for (int d = 0; d < 4; ++d) {
        const int rd = d * 16 + qc;
        const int el = rd * 64 + ((((ks * 2 + (g >> 1)) ^ (rd & 7)) << 3) + ((g & 1) << 2));
        short4v vf = *(const short4v*)&sVc[el];
        acc[d] = __builtin_amdgcn_mfma_f32_16x16x16bf16_1k(vf, pb[ks], acc[d], 0, 0, 0);
      }
    }
    __builtin_amdgcn_s_setprio(0);
    cur ^= 1;
  }
  float l = lsum;
  l += __shfl_xor(l, 16);
  l += __shfl_xor(l, 32);
  const float inv = 1.0f / l;
  unsigned short* Y = yb + (size_t)(b * 2048 + qrow) * 1024 + h * 64;
#pragma unroll
  for (int d = 0; d < 4; ++d) {
    ushort4v o;
#pragma unroll
    for (int j = 0; j < 4; ++j) o[j] = (unsigned short)bfbits(acc[d][j] * inv);
    *(ushort4v*)(Y + d * 16 + g * 4) = o;
  }
}

extern "C" void kernel_launch(void* const* d_in, const int* in_sizes, int n_in,
                              void* d_out, int out_size, void* d_ws, size_t ws_size,
                              hipStream_t stream) {
  const float* x  = (const float*)d_in[0];
  const float* Wq = (const float*)d_in[1];
  const float* Wk = (const float*)d_in[2];
  const float* Wv = (const float*)d_in[3];
  const float* Wo = (const float*)d_in[4];
  const float* qg = (const float*)d_in[5];
  float* out = (float*)d_out;

  char* ws = (char*)d_ws;
  const size_t NEED = 35127296;
  if (ws_size < NEED) return;
  unsigned short* xb   = (unsigned short*)(ws);                 // 8,388,608
  unsigned short* wqkv = (unsigned short*)(ws + 8388608);       // 3,145,728
  unsigned short* wo_b = (unsigned short*)(ws + 11534336);      // 2,097,152
  unsigned short* qbuf = (unsigned short*)(ws + 13631488);      // 8,388,608
  unsigned short* kbuf = (unsigned short*)(ws + 22020096);      // 2,097,152
  unsigned short* vtb  = (unsigned short*)(ws + 24117248);      // 2,097,152
  unsigned short* ybuf = (unsigned short*)(ws + 26214400);      // 8,388,608
  float*          tab  = (float*)        (ws + 34603008);       // 524,288

  prep_kernel<<<6912, 256, 0, stream>>>(x, Wq, Wk, Wv, Wo, xb, wqkv, wo_b, tab);
  gemm_qkv_kernel<<<64 * 12, 256, 0, stream>>>(xb, wqkv, tab, qg, qbuf, kbuf, vtb);
  attn_kernel<<<1024, 256, 0, stream>>>(qbuf, kbuf, vtb, ybuf, qg);
  gemm_bt_kernel<<<64 * 8, 256, 0, stream>>>(ybuf, wo_b, out, 4096, 1024, 1024, 8);
}